// Round 13
// baseline (205.994 us; speedup 1.0000x reference)
//
#include <hip/hip_runtime.h>
#include <math.h>

#define M_SPATIAL 2097152  // 128^3
#define MV4 (M_SPATIAL / 4)

__device__ __forceinline__ float wave_redf(float v) {
#pragma unroll
  for (int o = 32; o > 0; o >>= 1) v += __shfl_down(v, o, 64);
  return v;
}
__device__ __forceinline__ double wave_redd(double v) {
#pragma unroll
  for (int o = 32; o > 0; o >>= 1) v += __shfl_down(v, o, 64);
  return v;
}
// Forced 3-input min (VOP3 v_min3_f32); exact, order-independent.
__device__ __forceinline__ float min3f(float a, float b, float c) {
  float d;
  asm("v_min3_f32 %0, %1, %2, %3" : "=v"(d) : "v"(a), "v"(b), "v"(c));
  return d;
}

// part layout (doubles):
// [0..1023]=ce  [1024..2047]=p  [2048..3071]=pt  [3072..4095]=t  (1024 kAB
// blocks, blk>>9 = b)   [4096..4351]=dist (256 kCD blocks)
// g is stored TRANSPOSED: gT[b][yy][x][z].

// ---------------------------------------------------------------------------
// kAB v5: LDS-staged slab + round-8's PROVEN 16-chunk register scan.
// r10/r11/r12 post-mortems: structure correct, register budget was the bug.
//   r10: 32-elem arrays + cap128 -> spill (WRITE 150MB).
//   r12: 32-elem arrays + cap256 -> 248 VGPR -> 9% occupancy, latency-bound.
// v5: 16-elem arrays (~90 live regs) + __launch_bounds__(256,4) (cap 128,
// 4 waves/SIMD). Block = (b, yy, z-quarter): 128x x 32z, 18.4 KB LDS,
// 4 blocks/CU. All LDS patterns <=2-way bank aliasing (free).
// ---------------------------------------------------------------------------
__global__ __launch_bounds__(256, 4) void kAB(const int* __restrict__ y,
                                              const float* __restrict__ outputs,
                                              float* __restrict__ gT,
                                              double* __restrict__ part) {
  __shared__ int ysl[128 * 36];    // pitch 36 words (144B, 16B-aligned)
  __shared__ int lE[8][32];
  __shared__ int nE[8][32];
  __shared__ float sm[4][4];
  int blk = blockIdx.x;            // b*512 + yy*4 + zq
  int b  = blk >> 9;
  int yy = (blk >> 2) & 127;
  int zq = blk & 3;
  int t  = threadIdx.x;

  const int4*   y4  = (const int4*)y;
  const float4* xc4 = (const float4*)outputs + (size_t)(b * 2 + 1) * MV4;

  // ---- Stage slab (1024 int4 = 128x x 32z) + CE/dice on the fly.
  float ce = 0.f, ps = 0.f, pts = 0.f, tsum = 0.f;
#pragma unroll
  for (int r = 0; r < 4; ++r) {
    int i4 = t + r * 256;          // 0..1023
    int x  = i4 >> 3;              // 0..127
    int u  = i4 & 7;               // int4 within 32-z run
    size_t sp4 = (size_t)x * 4096 + (size_t)yy * 32 + (size_t)zq * 8 + u;
    int4  yv = y4[(size_t)b * MV4 + sp4];
    float4 xv = xc4[sp4];
#define ELEM(cc, yc)                                                        \
    {                                                                       \
      float tt = (yc == 1) ? 1.0f : 0.0f;                                   \
      float xx = xv.cc;                                                     \
      ce += fmaxf(xx, 0.0f) - xx * tt + log1pf(expf(-fabsf(xx)));           \
      float p = 1.0f / (1.0f + expf(-xx));                                  \
      ps += p; pts += p * tt; tsum += tt;                                   \
    }
    ELEM(x, yv.x) ELEM(y, yv.y) ELEM(z, yv.z) ELEM(w, yv.w)
#undef ELEM
    *(int4*)&ysl[x * 36 + u * 4] = yv;
  }
  __syncthreads();

  // ---- X-EDT: thread owns z-column zl (32 z), chunk c of 16 x (8 chunks).
  int zl = t & 31, c = t >> 5;
  int x0 = c * 16;
  int yb[16];
#pragma unroll
  for (int k = 0; k < 16; ++k) yb[k] = ysl[(x0 + k) * 36 + zl];

  int lastE = -200, nextE = 400;
#pragma unroll
  for (int k = 0; k < 16; ++k) lastE = (yb[k] == 1) ? lastE : (x0 + k);
#pragma unroll
  for (int k = 15; k >= 0; --k) nextE = (yb[k] == 1) ? nextE : (x0 + k);
  lE[c][zl] = lastE;
  nE[c][zl] = nextE;
  __syncthreads();

  int carryL = -200, carryN = 400;
#pragma unroll
  for (int q = 0; q < 7; ++q) {
    if (q < c)     carryL = max(carryL, lE[q][zl]);
    if (q + 1 > c) carryN = min(carryN, nE[q + 1][zl]);
  }

  float yy2f = (float)(yy * yy);
  float hinf = 1000000.f + yy2f;

  int df[16];
  int ll = carryL;
#pragma unroll
  for (int k = 0; k < 16; ++k) {
    ll = (yb[k] == 1) ? ll : (x0 + k);
    df[k] = min(x0 + k - ll, 200);
  }
  float* hsl = (float*)ysl;        // reuse in place (own slots only)
  int nn = carryN;
#pragma unroll
  for (int k = 15; k >= 0; --k) {
    nn = (yb[k] == 1) ? nn : (x0 + k);
    int m = min(df[k], min(nn - (x0 + k), 200));
    hsl[(x0 + k) * 36 + zl] = (m >= 128) ? hinf : ((float)(m * m) + yy2f);
  }
  __syncthreads();                 // cross-thread: writeout reads all slots

  // ---- Coalesced writeout into transposed gT[b][yy][x][z].
  float4* gT4 = (float4*)gT;
#pragma unroll
  for (int r = 0; r < 4; ++r) {
    int i4 = t + r * 256;
    int x  = i4 >> 3;
    int u  = i4 & 7;
    float4 v = *(float4*)&hsl[x * 36 + u * 4];
    gT4[(size_t)b * MV4 + (size_t)yy * 4096 + (size_t)x * 32 +
        (size_t)zq * 8 + u] = v;
  }

  // ---- CE/dice partials.
  float r0 = wave_redf(ce), r1 = wave_redf(ps), r2 = wave_redf(pts), r3 = wave_redf(tsum);
  int lane = t & 63, w = t >> 6;
  if (lane == 0) { sm[w][0] = r0; sm[w][1] = r1; sm[w][2] = r2; sm[w][3] = r3; }
  __syncthreads();
  if (t == 0) {
    part[blk]        = (double)(sm[0][0] + sm[1][0] + sm[2][0] + sm[3][0]);
    part[1024 + blk] = (double)(sm[0][1] + sm[1][1] + sm[2][1] + sm[3][1]);
    part[2048 + blk] = (double)(sm[0][2] + sm[1][2] + sm[2][2] + sm[3][2]);
    part[3072 + blk] = (double)(sm[0][3] + sm[1][3] + sm[2][3] + sm[3][3]);
  }
}

// ---------------------------------------------------------------------------
// kCD: fused Y+Z windowed-exact EDT + dist loss, one block per (b,x) slab.
// Unchanged from rounds 10-12 (validated: below profiling cutoff, absmax 0).
// Only the dist partial slot moved (part[4096+blk]).
// ---------------------------------------------------------------------------
__global__ __launch_bounds__(512, 1) void kCD(const float* __restrict__ gT,
                                              const float* __restrict__ od,
                                              double* __restrict__ part) {
  __shared__ float hl[144 * 129];   // 74.3 KB
  __shared__ float sred[8];
  int blk = blockIdx.x;             // b*128 + xx
  int b = blk >> 7, xx = blk & 127;
  int t = threadIdx.x;

  for (int idx = t; idx < 8 * 129; idx += 512) {
    hl[idx] = 1.0e9f;
    hl[136 * 129 + idx] = 1.0e9f;
  }
  const float4* gT4 = (const float4*)gT;
#pragma unroll
  for (int r = 0; r < 8; ++r) {
    int i4 = t + r * 512;           // 0..4095
    int yyi = i4 >> 5, u = i4 & 31;
    float4 v = gT4[(size_t)b * MV4 + (size_t)yyi * 4096 + (size_t)xx * 32 + u];
    float* p = &hl[(yyi + 8) * 129 + u * 4];
    p[0] = v.x; p[1] = v.y; p[2] = v.z; p[3] = v.w;
  }
  __syncthreads();

  // ---- Y pass: thread (z = t&127, ig = t>>7), 2 chunks x 16 y-outputs.
  int zcol = t & 127, ig = t >> 7;
  float dvy[2][16];
#pragma unroll
  for (int cb = 0; cb < 2; ++cb) {
    int ibase = ig * 32 + cb * 16;
    float best[16], mc[16];
#pragma unroll
    for (int k = 0; k < 16; ++k) {
      best[k] = 3.0e38f;
      mc[k] = -2.0f * (float)(ibase + k);
    }
    float jb = (float)(ibase - 8);
#pragma unroll 4
    for (int p = 0; p < 16; ++p) {
      float h0 = hl[(ibase + 2 * p) * 129 + zcol];
      float h1 = hl[(ibase + 2 * p + 1) * 129 + zcol];
      float j0 = jb + (float)(2 * p), j1 = jb + (float)(2 * p + 1);
#pragma unroll
      for (int k = 0; k < 16; ++k) {
        float v0 = fmaf(mc[k], j0, h0);
        float v1 = fmaf(mc[k], j1, h1);
        best[k] = min3f(v0, v1, best[k]);
      }
    }
    int ok = 1;
#pragma unroll
    for (int k = 0; k < 16; ++k) {
      int i = ibase + k;
      dvy[cb][k] = (float)(i * i) + best[k];
      float bnd = (float)min((k + 9) * (k + 9), (24 - k) * (24 - k));
      ok &= (dvy[cb][k] <= bnd);
    }
    if (!__all(ok)) {
#pragma unroll
      for (int k = 0; k < 16; ++k) best[k] = 3.0e38f;
#pragma unroll 2
      for (int j = 0; j < 128; j += 2) {
        float h0 = hl[(j + 8) * 129 + zcol];
        float h1 = hl[(j + 9) * 129 + zcol];
        float j0 = (float)j, j1 = (float)(j + 1);
#pragma unroll
        for (int k = 0; k < 16; ++k) {
          float v0 = fmaf(mc[k], j0, h0);
          float v1 = fmaf(mc[k], j1, h1);
          best[k] = min3f(v0, v1, best[k]);
        }
      }
#pragma unroll
      for (int k = 0; k < 16; ++k) {
        int i = ibase + k;
        dvy[cb][k] = (float)(i * i) + best[k];
      }
    }
  }
  __syncthreads();
  {
    float zq = (float)(zcol * zcol);
#pragma unroll
    for (int cb = 0; cb < 2; ++cb) {
      int ibase = ig * 32 + cb * 16;
#pragma unroll
      for (int k = 0; k < 16; ++k)
        hl[(zcol + 8) * 129 + (ibase + k)] = dvy[cb][k] + zq;
    }
  }
  __syncthreads();

  // ---- Z pass + dist: thread (y = t&127, izg = t>>7), 2 chunks x 16 z.
  int ycol = t & 127, izg = t >> 7;
  size_t odb = (size_t)(2 * b + 1) * M_SPATIAL + (size_t)xx * 16384 +
               (size_t)ycol * 128 + (size_t)izg * 32;
  const float4* o4 = (const float4*)(od + odb);
  float4 ovv[8];
#pragma unroll
  for (int r = 0; r < 8; ++r) ovv[r] = o4[r];
  const float* of = (const float*)ovv;

  float dist = 0.f;
#pragma unroll
  for (int cb = 0; cb < 2; ++cb) {
    int izb = izg * 32 + cb * 16;
    float best[16], mc[16];
#pragma unroll
    for (int k = 0; k < 16; ++k) {
      best[k] = 3.0e38f;
      mc[k] = -2.0f * (float)(izb + k);
    }
    float jb = (float)(izb - 8);
#pragma unroll 4
    for (int p = 0; p < 16; ++p) {
      float h0 = hl[(izb + 2 * p) * 129 + ycol];
      float h1 = hl[(izb + 2 * p + 1) * 129 + ycol];
      float j0 = jb + (float)(2 * p), j1 = jb + (float)(2 * p + 1);
#pragma unroll
      for (int k = 0; k < 16; ++k) {
        float v0 = fmaf(mc[k], j0, h0);
        float v1 = fmaf(mc[k], j1, h1);
        best[k] = min3f(v0, v1, best[k]);
      }
    }
    float dv[16];
    int ok = 1;
#pragma unroll
    for (int k = 0; k < 16; ++k) {
      int i = izb + k;
      dv[k] = (float)(i * i) + best[k];
      float bnd = (float)min((k + 9) * (k + 9), (24 - k) * (24 - k));
      ok &= (dv[k] <= bnd);
    }
    if (!__all(ok)) {
#pragma unroll
      for (int k = 0; k < 16; ++k) best[k] = 3.0e38f;
#pragma unroll 2
      for (int j = 0; j < 128; j += 2) {
        float h0 = hl[(j + 8) * 129 + ycol];
        float h1 = hl[(j + 9) * 129 + ycol];
        float j0 = (float)j, j1 = (float)(j + 1);
#pragma unroll
        for (int k = 0; k < 16; ++k) {
          float v0 = fmaf(mc[k], j0, h0);
          float v1 = fmaf(mc[k], j1, h1);
          best[k] = min3f(v0, v1, best[k]);
        }
      }
#pragma unroll
      for (int k = 0; k < 16; ++k) {
        int i = izb + k;
        dv[k] = (float)(i * i) + best[k];
      }
    }
#pragma unroll
    for (int k = 0; k < 16; ++k) {
      if (dv[k] > 0.f) dist += fabsf(of[cb * 16 + k] - sqrtf(dv[k]));
    }
  }
  float r = wave_redf(dist);
  int lane = t & 63, w = t >> 6;
  if (lane == 0) sred[w] = r;
  __syncthreads();
  if (t == 0) {
    float s = 0.f;
#pragma unroll
    for (int q = 0; q < 8; ++q) s += sred[q];
    part[4096 + blk] = (double)s;
  }
}

// ---------------------------------------------------------------------------
// k_final: reduce partials (4x1024 ce/dice slots, 256 dist slots) -> loss.
// kAB blocks 0..511 are b=0, 512..1023 are b=1.
// ---------------------------------------------------------------------------
__global__ __launch_bounds__(256) void k_final(const double* __restrict__ part,
                                               const float* __restrict__ wptr,
                                               float* __restrict__ out) {
  int i = threadIdx.x;
  double ce  = part[i] + part[i + 256] + part[i + 512] + part[i + 768];
  double p0  = part[1024 + i] + part[1024 + i + 256];
  double p1  = part[1536 + i] + part[1536 + i + 256];
  double pt0 = part[2048 + i] + part[2048 + i + 256];
  double pt1 = part[2560 + i] + part[2560 + i + 256];
  double t0  = part[3072 + i] + part[3072 + i + 256];
  double t1  = part[3584 + i] + part[3584 + i + 256];
  double ds  = part[4096 + i];   // 256 kCD blocks

  ce = wave_redd(ce); p0 = wave_redd(p0); p1 = wave_redd(p1);
  pt0 = wave_redd(pt0); pt1 = wave_redd(pt1);
  t0 = wave_redd(t0); t1 = wave_redd(t1); ds = wave_redd(ds);

  __shared__ double sm[4][8];
  int lane = threadIdx.x & 63, w = threadIdx.x >> 6;
  if (lane == 0) {
    sm[w][0] = ce; sm[w][1] = p0; sm[w][2] = p1; sm[w][3] = pt0;
    sm[w][4] = pt1; sm[w][5] = t0; sm[w][6] = t1; sm[w][7] = ds;
  }
  __syncthreads();
  if (threadIdx.x == 0) {
    double a[8];
    for (int q = 0; q < 8; ++q) a[q] = sm[0][q] + sm[1][q] + sm[2][q] + sm[3][q];
    double cem = a[0] / 4194304.0;
    double dice0 = (2.0 * a[3] + 1.0) / (a[1] + a[5] + 1.0);
    double dice1 = (2.0 * a[4] + 1.0) / (a[2] + a[6] + 1.0);
    double ldice = 1.0 - 0.5 * (dice0 + dice1);
    double msum = a[5] + a[6];
    double ldist = (msum == 0.0) ? 0.0 : a[7] / fmax(msum, 1e-12);
    out[0] = (float)(cem + ldice + (double)wptr[0] * ldist);
  }
}

extern "C" void kernel_launch(void* const* d_in, const int* in_sizes, int n_in,
                              void* d_out, int out_size, void* d_ws, size_t ws_size,
                              hipStream_t stream) {
  const float* outputs      = (const float*)d_in[0];
  const float* outputs_dist = (const float*)d_in[1];
  const int*   y            = (const int*)d_in[2];
  const float* wptr         = (const float*)d_in[3];
  float* out = (float*)d_out;

  double* part = (double*)d_ws;                    // 4352 doubles
  float* gT = (float*)((char*)d_ws + 65536);       // 16 MiB transposed h field

  kAB<<<1024, 256, 0, stream>>>(y, outputs, gT, part);     // X + CE/dice
  kCD<<<256, 512, 0, stream>>>(gT, outputs_dist, part);    // fused Y+Z + dist
  k_final<<<1, 256, 0, stream>>>(part, wptr, out);
}

// Round 14
// 138.659 us; speedup vs baseline: 1.4856x; 1.4856x over previous
//
#include <hip/hip_runtime.h>
#include <math.h>

#define M_SPATIAL 2097152  // 128^3

__device__ __forceinline__ float wave_redf(float v) {
#pragma unroll
  for (int o = 32; o > 0; o >>= 1) v += __shfl_down(v, o, 64);
  return v;
}
__device__ __forceinline__ double wave_redd(double v) {
#pragma unroll
  for (int o = 32; o > 0; o >>= 1) v += __shfl_down(v, o, 64);
  return v;
}
// Forced 3-input min (VOP3 v_min3_f32); exact, order-independent.
__device__ __forceinline__ float min3f(float a, float b, float c) {
  float d;
  asm("v_min3_f32 %0, %1, %2, %3" : "=v"(d) : "v"(a), "v"(b), "v"(c));
  return d;
}

// part layout (doubles):
// [0..1023]=ce  [1024..2047]=p  [2048..3071]=pt  [3072..4095]=t
// [4096..4351]=dist (256 kCD blocks)

// ---------------------------------------------------------------------------
// kAB: X-axis EDT (blocked parallel scan) FUSED with CE + dice partials.
// xc is already batch-offset -> spatial-only index sp (round-2 OOB lesson).
// Writes h = gX + y^2 for the Y pass.
// ROUND-9 VERBATIM (measured 139.6 us total). The LDS-slab rewrite of this
// kernel (r10-r13) is structurally sound but unlandable: the register
// allocator spills at cap 128 (r10), balloons to 248 uncapped (r12), and
// picks 64+spill at min-waves=4 (r13). Strided version stands.
// ---------------------------------------------------------------------------
__global__ __launch_bounds__(256) void kAB(const int* __restrict__ y,
                                           const float* __restrict__ outputs,
                                           float* __restrict__ g,
                                           double* __restrict__ part) {
  int blk = blockIdx.x;            // b*512 + yy*4 + zq
  int b  = blk >> 9;
  int yy = (blk >> 2) & 127;
  int zq = blk & 3;
  int t  = threadIdx.x;
  int c  = t >> 5;                 // x-chunk 0..7 (16 x each)
  int zl = t & 31;                 // z within 32-chunk
  int x0 = c * 16;
  size_t sp   = (size_t)yy * 128 + (size_t)zq * 32 + zl;    // spatial-only
  size_t base = (size_t)b * M_SPATIAL + sp;                 // batch + spatial
  const float* xc = outputs + (size_t)(b * 2 + 1) * M_SPATIAL;

  int yb[16];
  float xv[16];
#pragma unroll
  for (int k = 0; k < 16; ++k) yb[k] = y[base + (size_t)(x0 + k) * 16384];
#pragma unroll
  for (int k = 0; k < 16; ++k) xv[k] = xc[sp + (size_t)(x0 + k) * 16384];

  int lastE = -200, nextE = 400;
#pragma unroll
  for (int k = 0; k < 16; ++k) lastE = (yb[k] == 1) ? lastE : (x0 + k);
#pragma unroll
  for (int k = 15; k >= 0; --k) nextE = (yb[k] == 1) ? nextE : (x0 + k);

  __shared__ int lE[8][32];
  __shared__ int nE[8][32];
  lE[c][zl] = lastE;
  nE[c][zl] = nextE;
  __syncthreads();

  int carryL = -200, carryN = 400;
#pragma unroll
  for (int q = 0; q < 7; ++q) {
    if (q < c)     carryL = max(carryL, lE[q][zl]);
    if (q + 1 > c) carryN = min(carryN, nE[q + 1][zl]);
  }

  float yy2f = (float)(yy * yy);
  float hinf = 1000000.f + yy2f;

  int df[16];
  int ll = carryL;
#pragma unroll
  for (int k = 0; k < 16; ++k) {
    ll = (yb[k] == 1) ? ll : (x0 + k);
    df[k] = min(x0 + k - ll, 200);
  }
  float ov[16];
  int nn = carryN;
#pragma unroll
  for (int k = 15; k >= 0; --k) {
    nn = (yb[k] == 1) ? nn : (x0 + k);
    int m = min(df[k], min(nn - (x0 + k), 200));
    ov[k] = (m >= 128) ? hinf : ((float)(m * m) + yy2f);
  }
#pragma unroll
  for (int k = 0; k < 16; ++k) g[base + (size_t)(x0 + k) * 16384] = ov[k];

  float ce = 0.f, ps = 0.f, pts = 0.f, tsum = 0.f;
#pragma unroll
  for (int k = 0; k < 16; ++k) {
    float tt = (yb[k] == 1) ? 1.0f : 0.0f;
    float xx = xv[k];
    ce += fmaxf(xx, 0.0f) - xx * tt + log1pf(expf(-fabsf(xx)));
    float p = 1.0f / (1.0f + expf(-xx));
    ps += p; pts += p * tt; tsum += tt;
  }
  float r0 = wave_redf(ce), r1 = wave_redf(ps), r2 = wave_redf(pts), r3 = wave_redf(tsum);
  __shared__ float sm[4][4];
  int lane = t & 63, w = t >> 6;
  if (lane == 0) { sm[w][0] = r0; sm[w][1] = r1; sm[w][2] = r2; sm[w][3] = r3; }
  __syncthreads();
  if (t == 0) {
    part[blk]        = (double)(sm[0][0] + sm[1][0] + sm[2][0] + sm[3][0]);
    part[1024 + blk] = (double)(sm[0][1] + sm[1][1] + sm[2][1] + sm[3][1]);
    part[2048 + blk] = (double)(sm[0][2] + sm[1][2] + sm[2][2] + sm[3][2]);
    part[3072 + blk] = (double)(sm[0][3] + sm[1][3] + sm[2][3] + sm[3][3]);
  }
}

// ---------------------------------------------------------------------------
// kCD: fused Y+Z windowed-exact EDT + dist loss, one block per (b,x) slab.
// Full slab in LDS (hl[144][129], halo rows = 1e9); Y pass windowed with
// exactness certificate + full-scan fallback; transposed in-place rewrite;
// Z pass same. ROUND-9 VERBATIM (below profiling cutoff there).
// ---------------------------------------------------------------------------
__global__ __launch_bounds__(512, 1) void kCD(const float* __restrict__ g,
                                              const float* __restrict__ od,
                                              double* __restrict__ part) {
  __shared__ float hl[144 * 129];   // 74.3 KB
  __shared__ float sred[8];
  int blk = blockIdx.x;             // b*128 + xx
  int b = blk >> 7, xx = blk & 127;
  int t = threadIdx.x;
  size_t rb = (size_t)b * M_SPATIAL + (size_t)xx * 16384;

  // Pad rows (8 bottom, 8 top) with a value that can never win.
  for (int idx = t; idx < 8 * 129; idx += 512) {
    hl[idx] = 1.0e9f;
    hl[136 * 129 + idx] = 1.0e9f;
  }
  // Stage the slab: 4096 float4 coalesced reads, 4 scalar LDS writes each.
  const float4* g4 = (const float4*)(g + rb);
#pragma unroll
  for (int r = 0; r < 8; ++r) {
    int i4 = t + r * 512;           // 0..4095
    float4 v = g4[i4];
    int yy = i4 >> 5, z4 = (i4 & 31) * 4;
    float* p = &hl[(yy + 8) * 129 + z4];
    p[0] = v.x; p[1] = v.y; p[2] = v.z; p[3] = v.w;
  }
  __syncthreads();

  // ---- Y pass: thread (z = t&127, ig = t>>7), 2 chunks x 16 y-outputs.
  int zcol = t & 127, ig = t >> 7;
  float dvy[2][16];
#pragma unroll
  for (int cb = 0; cb < 2; ++cb) {
    int ibase = ig * 32 + cb * 16;
    float best[16], mc[16];
#pragma unroll
    for (int k = 0; k < 16; ++k) {
      best[k] = 3.0e38f;
      mc[k] = -2.0f * (float)(ibase + k);
    }
    float jb = (float)(ibase - 8);
#pragma unroll 4
    for (int p = 0; p < 16; ++p) {     // rows [ibase, ibase+32) = yj+8
      float h0 = hl[(ibase + 2 * p) * 129 + zcol];
      float h1 = hl[(ibase + 2 * p + 1) * 129 + zcol];
      float j0 = jb + (float)(2 * p), j1 = jb + (float)(2 * p + 1);
#pragma unroll
      for (int k = 0; k < 16; ++k) {
        float v0 = fmaf(mc[k], j0, h0);
        float v1 = fmaf(mc[k], j1, h1);
        best[k] = min3f(v0, v1, best[k]);
      }
    }
    int ok = 1;
#pragma unroll
    for (int k = 0; k < 16; ++k) {
      int i = ibase + k;
      dvy[cb][k] = (float)(i * i) + best[k];
      float bnd = (float)min((k + 9) * (k + 9), (24 - k) * (24 - k));
      ok &= (dvy[cb][k] <= bnd);
    }
    if (!__all(ok)) {                   // exactness not certified -> full scan
#pragma unroll
      for (int k = 0; k < 16; ++k) best[k] = 3.0e38f;
#pragma unroll 2
      for (int j = 0; j < 128; j += 2) {
        float h0 = hl[(j + 8) * 129 + zcol];
        float h1 = hl[(j + 9) * 129 + zcol];
        float j0 = (float)j, j1 = (float)(j + 1);
#pragma unroll
        for (int k = 0; k < 16; ++k) {
          float v0 = fmaf(mc[k], j0, h0);
          float v1 = fmaf(mc[k], j1, h1);
          best[k] = min3f(v0, v1, best[k]);
        }
      }
#pragma unroll
      for (int k = 0; k < 16; ++k) {
        int i = ibase + k;
        dvy[cb][k] = (float)(i * i) + best[k];
      }
    }
  }
  __syncthreads();                      // ALL h reads complete
  // Transposed in-place write: hl[z+8][y] = dY^2 + z^2 (payload for Z pass).
  {
    float zq = (float)(zcol * zcol);
#pragma unroll
    for (int cb = 0; cb < 2; ++cb) {
      int ibase = ig * 32 + cb * 16;
#pragma unroll
      for (int k = 0; k < 16; ++k)
        hl[(zcol + 8) * 129 + (ibase + k)] = dvy[cb][k] + zq;
    }
  }
  __syncthreads();

  // ---- Z pass + dist: thread (y = t&127, izg = t>>7), 2 chunks x 16 z.
  int ycol = t & 127, izg = t >> 7;
  size_t odb = (size_t)(2 * b + 1) * M_SPATIAL + (size_t)xx * 16384 +
               (size_t)ycol * 128 + (size_t)izg * 32;
  const float4* o4 = (const float4*)(od + odb);
  float4 ovv[8];
#pragma unroll
  for (int r = 0; r < 8; ++r) ovv[r] = o4[r];
  const float* of = (const float*)ovv;

  float dist = 0.f;
#pragma unroll
  for (int cb = 0; cb < 2; ++cb) {
    int izb = izg * 32 + cb * 16;
    float best[16], mc[16];
#pragma unroll
    for (int k = 0; k < 16; ++k) {
      best[k] = 3.0e38f;
      mc[k] = -2.0f * (float)(izb + k);
    }
    float jb = (float)(izb - 8);
#pragma unroll 4
    for (int p = 0; p < 16; ++p) {     // rows [izb, izb+32) = zj+8
      float h0 = hl[(izb + 2 * p) * 129 + ycol];
      float h1 = hl[(izb + 2 * p + 1) * 129 + ycol];
      float j0 = jb + (float)(2 * p), j1 = jb + (float)(2 * p + 1);
#pragma unroll
      for (int k = 0; k < 16; ++k) {
        float v0 = fmaf(mc[k], j0, h0);
        float v1 = fmaf(mc[k], j1, h1);
        best[k] = min3f(v0, v1, best[k]);
      }
    }
    float dv[16];
    int ok = 1;
#pragma unroll
    for (int k = 0; k < 16; ++k) {
      int i = izb + k;
      dv[k] = (float)(i * i) + best[k];
      float bnd = (float)min((k + 9) * (k + 9), (24 - k) * (24 - k));
      ok &= (dv[k] <= bnd);
    }
    if (!__all(ok)) {
#pragma unroll
      for (int k = 0; k < 16; ++k) best[k] = 3.0e38f;
#pragma unroll 2
      for (int j = 0; j < 128; j += 2) {
        float h0 = hl[(j + 8) * 129 + ycol];
        float h1 = hl[(j + 9) * 129 + ycol];
        float j0 = (float)j, j1 = (float)(j + 1);
#pragma unroll
        for (int k = 0; k < 16; ++k) {
          float v0 = fmaf(mc[k], j0, h0);
          float v1 = fmaf(mc[k], j1, h1);
          best[k] = min3f(v0, v1, best[k]);
        }
      }
#pragma unroll
      for (int k = 0; k < 16; ++k) {
        int i = izb + k;
        dv[k] = (float)(i * i) + best[k];
      }
    }
#pragma unroll
    for (int k = 0; k < 16; ++k) {
      if (dv[k] > 0.f) dist += fabsf(of[cb * 16 + k] - sqrtf(dv[k]));
    }
  }
  float r = wave_redf(dist);
  int lane = t & 63, w = t >> 6;
  if (lane == 0) sred[w] = r;
  __syncthreads();
  if (t == 0) {
    float s = 0.f;
#pragma unroll
    for (int q = 0; q < 8; ++q) s += sred[q];
    part[4096 + blk] = (double)s;
  }
}

// ---------------------------------------------------------------------------
// k_final: reduce partials (1024 ce/dice slots, 256 dist slots) -> loss.
// ---------------------------------------------------------------------------
__global__ __launch_bounds__(256) void k_final(const double* __restrict__ part,
                                               const float* __restrict__ wptr,
                                               float* __restrict__ out) {
  int i = threadIdx.x;
  double ce  = part[i] + part[i + 256] + part[i + 512] + part[i + 768];
  double p0  = part[1024 + i] + part[1024 + i + 256];
  double p1  = part[1536 + i] + part[1536 + i + 256];
  double pt0 = part[2048 + i] + part[2048 + i + 256];
  double pt1 = part[2560 + i] + part[2560 + i + 256];
  double t0  = part[3072 + i] + part[3072 + i + 256];
  double t1  = part[3584 + i] + part[3584 + i + 256];
  double ds  = part[4096 + i];   // 256 kCD blocks, one slot per thread

  ce = wave_redd(ce); p0 = wave_redd(p0); p1 = wave_redd(p1);
  pt0 = wave_redd(pt0); pt1 = wave_redd(pt1);
  t0 = wave_redd(t0); t1 = wave_redd(t1); ds = wave_redd(ds);

  __shared__ double sm[4][8];
  int lane = threadIdx.x & 63, w = threadIdx.x >> 6;
  if (lane == 0) {
    sm[w][0] = ce; sm[w][1] = p0; sm[w][2] = p1; sm[w][3] = pt0;
    sm[w][4] = pt1; sm[w][5] = t0; sm[w][6] = t1; sm[w][7] = ds;
  }
  __syncthreads();
  if (threadIdx.x == 0) {
    double a[8];
    for (int q = 0; q < 8; ++q) a[q] = sm[0][q] + sm[1][q] + sm[2][q] + sm[3][q];
    double cem = a[0] / 4194304.0;
    double dice0 = (2.0 * a[3] + 1.0) / (a[1] + a[5] + 1.0);
    double dice1 = (2.0 * a[4] + 1.0) / (a[2] + a[6] + 1.0);
    double ldice = 1.0 - 0.5 * (dice0 + dice1);
    double msum = a[5] + a[6];
    double ldist = (msum == 0.0) ? 0.0 : a[7] / fmax(msum, 1e-12);
    out[0] = (float)(cem + ldice + (double)wptr[0] * ldist);
  }
}

extern "C" void kernel_launch(void* const* d_in, const int* in_sizes, int n_in,
                              void* d_out, int out_size, void* d_ws, size_t ws_size,
                              hipStream_t stream) {
  const float* outputs      = (const float*)d_in[0];
  const float* outputs_dist = (const float*)d_in[1];
  const int*   y            = (const int*)d_in[2];
  const float* wptr         = (const float*)d_in[3];
  float* out = (float*)d_out;

  double* part = (double*)d_ws;                    // 4352 doubles
  float* g = (float*)((char*)d_ws + 65536);        // 16 MiB h field

  kAB<<<1024, 256, 0, stream>>>(y, outputs, g, part);      // X + CE/dice
  kCD<<<256, 512, 0, stream>>>(g, outputs_dist, part);     // fused Y+Z + dist
  k_final<<<1, 256, 0, stream>>>(part, wptr, out);
}